// Round 4
// baseline (199.261 us; speedup 1.0000x reference)
//
#include <hip/hip_runtime.h>
#include <math.h>

#define BB 64
#define RR 2048
#define HH 1024
#define EE 512
#define DD 1024
#define RC 32           // r-chunks (blocks per b) in fused kernel
#define RPB (RR / RC)   // 64 rows per block
#define RPW (RPB / 4)   // 16 rows per wave
#define MB 4            // b's per block in k_wh

typedef float f32x4 __attribute__((ext_vector_type(4)));

__device__ __forceinline__ float fast_tanh(float x) {
    // tanh(x) = 1 - 2/(exp(2x)+1); exact limits at +/-inf
    float e = __expf(2.0f * x);
    return 1.0f - 2.0f * __builtin_amdgcn_rcpf(e + 1.0f);
}

__device__ __forceinline__ f32x4 fma4(float a, f32x4 f, f32x4 c) {
    c.x = fmaf(a, f.x, c.x);
    c.y = fmaf(a, f.y, c.y);
    c.z = fmaf(a, f.z, c.z);
    c.w = fmaf(a, f.w, c.w);
    return c;
}

// K1: wh[b][e] = sum_h hidden[b][h] * w_h[h][e]
// grid (B/MB, E/64), block 256 = 4 waves; wave owns h-segment of 256, MB b's at once.
__global__ __launch_bounds__(256) void k_wh(const float* __restrict__ hidden,
                                            const float* __restrict__ w_h,
                                            float* __restrict__ wh) {
    __shared__ float sh[MB][HH];       // 16 KB
    __shared__ float sred[4][MB][64];  // 4 KB
    const int b0 = blockIdx.x * MB;
    const int t = threadIdx.x;
    const int lane = t & 63, hseg = t >> 6;
    const int e = blockIdx.y * 64 + lane;
    for (int idx = t; idx < MB * HH; idx += 256)
        ((float*)sh)[idx] = hidden[b0 * HH + idx];
    __syncthreads();
    const int h0 = hseg * 256;
    float acc[MB] = {0.f, 0.f, 0.f, 0.f};
#pragma unroll 4
    for (int h = 0; h < 256; ++h) {
        const float wv = w_h[(h0 + h) * EE + e];
#pragma unroll
        for (int b = 0; b < MB; ++b) acc[b] = fmaf(sh[b][h0 + h], wv, acc[b]);
    }
#pragma unroll
    for (int b = 0; b < MB; ++b) sred[hseg][b][lane] = acc[b];
    __syncthreads();
    if (t < MB * 64) {
        const int b = t >> 6, l = t & 63;
        wh[(b0 + b) * EE + blockIdx.y * 64 + l] =
            (sred[0][b][l] + sred[1][b][l]) + (sred[2][b][l] + sred[3][b][l]);
    }
}

// Fused: per (rc, b) block; each wave owns 16 rows end-to-end (no mid barrier):
//   per row: w = exp(tanh-dot + mask)  then  acc += w * feats[row][:]
// Partial num reduced across the 4 waves via LDS at the end.
__global__ __launch_bounds__(256) void k_fused(const float* __restrict__ p_att,
                                               const float* __restrict__ feats,
                                               const float* __restrict__ wh,
                                               const float* __restrict__ w_alpha,
                                               const float* __restrict__ mask,
                                               float* __restrict__ num,
                                               float* __restrict__ den) {
    __shared__ float snum[4][DD];  // 16 KB
    __shared__ float sden[4];
    const int rc = blockIdx.x, b = blockIdx.y;
    const int t = threadIdx.x, wave = t >> 6, lane = t & 63;

    const float* __restrict__ whb = wh + b * EE;
    const f32x4 wh0 = *(const f32x4*)(whb + lane * 4);
    const f32x4 wh1 = *(const f32x4*)(whb + 256 + lane * 4);
    const f32x4 wa0 = *(const f32x4*)(w_alpha + lane * 4);
    const f32x4 wa1 = *(const f32x4*)(w_alpha + 256 + lane * 4);

    const long long row0 = (long long)b * RR + rc * RPB + wave * RPW;
    const f32x4* __restrict__ pb = (const f32x4*)(p_att + row0 * EE);
    const f32x4* __restrict__ fb = (const f32x4*)(feats + row0 * DD);

    f32x4 acc0 = {0.f, 0.f, 0.f, 0.f}, acc1 = acc0, acc2 = acc0, acc3 = acc0;
    float dsum = 0.f;
#pragma unroll 2
    for (int rr = 0; rr < RPW; ++rr) {
        f32x4 p0 = pb[rr * (EE / 4) + lane];
        f32x4 p1 = pb[rr * (EE / 4) + 64 + lane];
        float s;
        s = fast_tanh(p0.x + wh0.x) * wa0.x;
        s = fmaf(fast_tanh(p0.y + wh0.y), wa0.y, s);
        s = fmaf(fast_tanh(p0.z + wh0.z), wa0.z, s);
        s = fmaf(fast_tanh(p0.w + wh0.w), wa0.w, s);
        s = fmaf(fast_tanh(p1.x + wh1.x), wa1.x, s);
        s = fmaf(fast_tanh(p1.y + wh1.y), wa1.y, s);
        s = fmaf(fast_tanh(p1.z + wh1.z), wa1.z, s);
        s = fmaf(fast_tanh(p1.w + wh1.w), wa1.w, s);
#pragma unroll
        for (int off = 32; off; off >>= 1) s += __shfl_xor(s, off);
        const float w = __expf(s + mask[row0 + rr]);
        dsum += w;
        const f32x4* __restrict__ fr = fb + rr * (DD / 4);
        acc0 = fma4(w, fr[lane], acc0);
        acc1 = fma4(w, fr[64 + lane], acc1);
        acc2 = fma4(w, fr[128 + lane], acc2);
        acc3 = fma4(w, fr[192 + lane], acc3);
    }
    *(f32x4*)&snum[wave][0 + lane * 4] = acc0;
    *(f32x4*)&snum[wave][256 + lane * 4] = acc1;
    *(f32x4*)&snum[wave][512 + lane * 4] = acc2;
    *(f32x4*)&snum[wave][768 + lane * 4] = acc3;
    if (lane == 0) sden[wave] = dsum;
    __syncthreads();
    // block-level reduce: thread t owns d = t*4 .. t*4+3
    f32x4 r0 = *(const f32x4*)&snum[0][t * 4];
    f32x4 r1 = *(const f32x4*)&snum[1][t * 4];
    f32x4 r2 = *(const f32x4*)&snum[2][t * 4];
    f32x4 r3 = *(const f32x4*)&snum[3][t * 4];
    f32x4 r = (r0 + r1) + (r2 + r3);
    ((f32x4*)(num + (long long)(b * RC + rc) * DD))[t] = r;
    if (t == 0) den[b * RC + rc] = (sden[0] + sden[1]) + (sden[2] + sden[3]);
}

// K3: out[b][d] = sum_rc num[b][rc][d] / sum_rc den[b][rc]
__global__ __launch_bounds__(256) void k_out(const float* __restrict__ num,
                                             const float* __restrict__ den,
                                             float* __restrict__ out) {
    const int idx = blockIdx.x * 256 + threadIdx.x;  // b*D + d
    const int b = idx >> 10;
    const int d = idx & 1023;
    float ds = 0.f;
#pragma unroll
    for (int rc = 0; rc < RC; ++rc) ds += den[b * RC + rc];
    float ns = 0.f;
#pragma unroll
    for (int rc = 0; rc < RC; ++rc)
        ns += num[((long long)(b * RC + rc) << 10) + d];
    out[idx] = ns / ds;
}

extern "C" void kernel_launch(void* const* d_in, const int* in_sizes, int n_in,
                              void* d_out, int out_size, void* d_ws, size_t ws_size,
                              hipStream_t stream) {
    const float* hidden  = (const float*)d_in[0];  // [B,H]
    const float* feats   = (const float*)d_in[1];  // [B,R,D]
    const float* p_att   = (const float*)d_in[2];  // [B,R,E]
    const float* mask    = (const float*)d_in[3];  // [B,R]
    const float* w_h     = (const float*)d_in[4];  // [H,E]
    const float* w_alpha = (const float*)d_in[5];  // [E]
    float* out = (float*)d_out;                    // [B,D]

    char* ws = (char*)d_ws;
    float* wh  = (float*)(ws);                               // 64*512*4 = 128 KB
    float* num = (float*)(ws + (size_t)131072);              // 64*32*1024*4 = 8 MB
    float* den = (float*)(ws + (size_t)(131072 + 8388608));  // 64*32*4 = 8 KB

    k_wh<<<dim3(BB / MB, EE / 64), 256, 0, stream>>>(hidden, w_h, wh);
    k_fused<<<dim3(RC, BB), 256, 0, stream>>>(p_att, feats, wh, w_alpha, mask, num, den);
    k_out<<<(BB * DD) / 256, 256, 0, stream>>>(num, den, out);
}

// Round 5
// 164.281 us; speedup vs baseline: 1.2129x; 1.2129x over previous
//
#include <hip/hip_runtime.h>
#include <math.h>

#define BB 64
#define RR 2048
#define HH 1024
#define EE 512
#define DD 1024
#define RC 16           // r-chunks (blocks per b) in fused kernel
#define RPB (RR / RC)   // 128 rows per block
#define RPW (RPB / 4)   // 32 rows per wave
#define MB 4            // b's per block in k_wh

typedef float f32x4 __attribute__((ext_vector_type(4)));

__device__ __forceinline__ float fast_tanh(float x) {
    // tanh(x) = 1 - 2/(exp(2x)+1); exact limits at +/-inf
    float e = __expf(2.0f * x);
    return 1.0f - 2.0f * __builtin_amdgcn_rcpf(e + 1.0f);
}

// K1: wh[b][e] = sum_h hidden[b][h] * w_h[h][e]
// grid (B/MB, E/64), block 256 = 4 waves; wave owns h-segment of 256, MB b's at once.
__global__ __launch_bounds__(256) void k_wh(const float* __restrict__ hidden,
                                            const float* __restrict__ w_h,
                                            float* __restrict__ wh) {
    __shared__ float sh[MB][HH];       // 16 KB
    __shared__ float sred[4][MB][64];  // 4 KB
    const int b0 = blockIdx.x * MB;
    const int t = threadIdx.x;
    const int lane = t & 63, hseg = t >> 6;
    const int e = blockIdx.y * 64 + lane;
    for (int idx = t; idx < MB * HH; idx += 256)
        ((float*)sh)[idx] = hidden[b0 * HH + idx];
    __syncthreads();
    const int h0 = hseg * 256;
    float acc[MB] = {0.f, 0.f, 0.f, 0.f};
#pragma unroll 4
    for (int h = 0; h < 256; ++h) {
        const float wv = w_h[(h0 + h) * EE + e];
#pragma unroll
        for (int b = 0; b < MB; ++b) acc[b] = fmaf(sh[b][h0 + h], wv, acc[b]);
    }
#pragma unroll
    for (int b = 0; b < MB; ++b) sred[hseg][b][lane] = acc[b];
    __syncthreads();
    if (t < MB * 64) {
        const int b = t >> 6, l = t & 63;
        wh[(b0 + b) * EE + blockIdx.y * 64 + l] =
            (sred[0][b][l] + sred[1][b][l]) + (sred[2][b][l] + sred[3][b][l]);
    }
}

// Fused K2+K3+K4: per (b, rc) block of RPB rows:
//   phase 1: w[r] = exp(logit[r] + mask[r])   (no max subtraction -- logits bounded)
//   phase 2: num[d] = sum_r w[r] * feats[r][d];  den = sum_r w[r]
__global__ __launch_bounds__(256) void k_fused(const float* __restrict__ p_att,
                                               const float* __restrict__ feats,
                                               const float* __restrict__ wh,
                                               const float* __restrict__ w_alpha,
                                               const float* __restrict__ mask,
                                               float* __restrict__ num,
                                               float* __restrict__ den) {
    __shared__ float sw[RPB];
    const int b = blockIdx.x, rc = blockIdx.y;
    const int t = threadIdx.x, wave = t >> 6, lane = t & 63;
    const int r0 = rc * RPB;

    // ---- phase 1: logits for this chunk (RPW rows per wave) ----
    const float* __restrict__ whb = wh + b * EE;
    const f32x4 wh0 = *(const f32x4*)(whb + lane * 4);
    const f32x4 wh1 = *(const f32x4*)(whb + 256 + lane * 4);
    const f32x4 wa0 = *(const f32x4*)(w_alpha + lane * 4);
    const f32x4 wa1 = *(const f32x4*)(w_alpha + 256 + lane * 4);
    const long long rowb = (long long)b * RR + r0 + wave * RPW;
    const f32x4* __restrict__ pb = (const f32x4*)(p_att + rowb * EE);
#pragma unroll 4
    for (int rr = 0; rr < RPW; ++rr) {
        f32x4 p0 = __builtin_nontemporal_load(pb + rr * (EE / 4) + lane);
        f32x4 p1 = __builtin_nontemporal_load(pb + rr * (EE / 4) + 64 + lane);
        float s;
        s = fast_tanh(p0.x + wh0.x) * wa0.x;
        s = fmaf(fast_tanh(p0.y + wh0.y), wa0.y, s);
        s = fmaf(fast_tanh(p0.z + wh0.z), wa0.z, s);
        s = fmaf(fast_tanh(p0.w + wh0.w), wa0.w, s);
        s = fmaf(fast_tanh(p1.x + wh1.x), wa1.x, s);
        s = fmaf(fast_tanh(p1.y + wh1.y), wa1.y, s);
        s = fmaf(fast_tanh(p1.z + wh1.z), wa1.z, s);
        s = fmaf(fast_tanh(p1.w + wh1.w), wa1.w, s);
#pragma unroll
        for (int off = 32; off; off >>= 1) s += __shfl_xor(s, off);
        if (lane == 0) sw[wave * RPW + rr] = __expf(s + mask[rowb + rr]);
    }
    __syncthreads();

    // ---- phase 2: weighted partial sum over feats; thread owns float4 of d ----
    const f32x4* __restrict__ fb =
        (const f32x4*)(feats + ((long long)b * RR + r0) * DD) + t;
    f32x4 acc = {0.f, 0.f, 0.f, 0.f};
#pragma unroll 8
    for (int r = 0; r < RPB; ++r) {
        const float a = sw[r];
        f32x4 f = __builtin_nontemporal_load(fb + r * (DD / 4));
        acc.x = fmaf(a, f.x, acc.x);
        acc.y = fmaf(a, f.y, acc.y);
        acc.z = fmaf(a, f.z, acc.z);
        acc.w = fmaf(a, f.w, acc.w);
    }
    ((f32x4*)(num + (long long)(b * RC + rc) * DD))[t] = acc;
    if (t == 0) {
        float d = 0.f;
#pragma unroll
        for (int r = 0; r < RPB; ++r) d += sw[r];
        den[b * RC + rc] = d;
    }
}

// K3: out[b][d] = sum_rc num[b][rc][d] / sum_rc den[b][rc]
__global__ __launch_bounds__(256) void k_out(const float* __restrict__ num,
                                             const float* __restrict__ den,
                                             float* __restrict__ out) {
    const int idx = blockIdx.x * 256 + threadIdx.x;  // b*D + d
    const int b = idx >> 10;
    const int d = idx & 1023;
    float ds = 0.f;
#pragma unroll
    for (int rc = 0; rc < RC; ++rc) ds += den[b * RC + rc];
    float ns = 0.f;
#pragma unroll
    for (int rc = 0; rc < RC; ++rc)
        ns += num[((long long)(b * RC + rc) << 10) + d];
    out[idx] = ns / ds;
}

extern "C" void kernel_launch(void* const* d_in, const int* in_sizes, int n_in,
                              void* d_out, int out_size, void* d_ws, size_t ws_size,
                              hipStream_t stream) {
    const float* hidden  = (const float*)d_in[0];  // [B,H]
    const float* feats   = (const float*)d_in[1];  // [B,R,D]
    const float* p_att   = (const float*)d_in[2];  // [B,R,E]
    const float* mask    = (const float*)d_in[3];  // [B,R]
    const float* w_h     = (const float*)d_in[4];  // [H,E]
    const float* w_alpha = (const float*)d_in[5];  // [E]
    float* out = (float*)d_out;                    // [B,D]

    char* ws = (char*)d_ws;
    float* wh  = (float*)(ws);                               // 64*512*4 = 128 KB
    float* num = (float*)(ws + (size_t)131072);              // 64*16*1024*4 = 4 MB
    float* den = (float*)(ws + (size_t)(131072 + 4194304));  // 64*16*4 = 4 KB

    k_wh<<<dim3(BB / MB, EE / 64), 256, 0, stream>>>(hidden, w_h, wh);
    k_fused<<<dim3(BB, RC), 256, 0, stream>>>(p_att, feats, wh, w_alpha, mask, num, den);
    k_out<<<(BB * DD) / 256, 256, 0, stream>>>(num, den, out);
}